// Round 11
// baseline (340.008 us; speedup 1.0000x reference)
//
#include <hip/hip_runtime.h>

// CustomRNN: B=2048, T=512, I=1, H=64.
// Evolution:
//  R0 172us LDS-BW | R2 158us 2 bpermute hops | R4 228us readlane issue
//  R5 134us DPP butterfly + LDS h (best) | R6 f16 dot2: no change
//  R7 252us reg-h spills | R9 171us shfl allgather (= ds_bpermute = same
//  LDS pipe, 2 serial hops). Conclusion: wall == L_chain; any step with
//  LDS-pipe hops floors at ~600-800cy.
//  R10: MFMA recurrence, zero cross-lane transport — #error fired on the
//      HOST pass (__has_builtin(amdgcn builtin) == 0 there). Untested.
//  R11 (this): R10 with the guard removed (builtins called directly, as
//      the guide's MFMA examples do).
//   One wave = 16 batches (N=16). h = B-fragments of
//   v_mfma_f32_16x16x16_f16. Documented layouts: A=A[l&15][4g+j],
//   B=B[4g+j][l&15], D=D[4g+j][l&15] (D: m89-verified) -> B == D lane
//   mapping -> D tile mt IS B tile kt=mt for the next step after in-lane
//   tanh+cvt. Per step: 16 MFMAs (4 M-tiles x 4 K-tiles, 2+2 split
//   accumulation), bias + x*W_ih folded into MFMA C-init (x prefetched
//   8 steps ahead, off-chain). No LDS, no barriers, no shuffles in the
//   recurrence. 128 independent wave-chains; wall = T * L_chain,
//   L_chain ~= 16 MFMA issue (~80cy) + 32 TRANS tanh (~130-250cy)
//   + packs ~= 250-350cy vs R5's 628.
//   Numerics: f16 W/h transport, f32 accumulate = R6-validated (2e-3).
//   Known risk: if the A-operand convention is swapped, this computes
//   W^T*h -> absmax ~0.4; fix = load W transposed next round.

typedef float v4f __attribute__((ext_vector_type(4)));
typedef float f32x4 __attribute__((ext_vector_type(4)));
typedef _Float16 f16;
typedef _Float16 f16x4 __attribute__((ext_vector_type(4)));

#define MFMA_AB(A, B, C) __builtin_amdgcn_mfma_f32_16x16x16f16((A), (B), (C), 0, 0, 0)

#define NB 16  // batches per wave (MFMA N dimension)

__global__ __launch_bounds__(64)
void rnn_fused(
    const float* __restrict__ x,      // [B, T, 1]
    const float* __restrict__ W_ih,   // [64, 1]
    const float* __restrict__ W_hh,   // [64, 64]
    const float* __restrict__ b_ih,   // [64]
    const float* __restrict__ b_hh,   // [64]
    const float* __restrict__ fc_w,   // [1, 64]
    const float* __restrict__ fc_b,   // [1]
    float* __restrict__ out,          // [B, 1]
    int B, int T)
{
    const int lane = threadIdx.x & 63;
    const int g    = lane >> 4;   // fragment outer group
    const int c15  = lane & 15;   // A row / B,D column (= local batch)
    const int b0   = blockIdx.x * NB;

    // ---- W_hh as A-fragments: A[mt][kt], lane holds
    // W[16*mt + c15][16*kt + 4*g + r], r=0..3 (4 consecutive k). 32 VGPRs.
    f16x4 wf[4][4];
#pragma unroll
    for (int mt = 0; mt < 4; ++mt) {
#pragma unroll
        for (int kt = 0; kt < 4; ++kt) {
            const v4f t = *(const v4f*)(W_hh + (16 * mt + c15) * 64 + 16 * kt + 4 * g);
            wf[mt][kt] = (f16x4){(f16)t.x, (f16)t.y, (f16)t.z, (f16)t.w};
        }
    }

    // ---- per-lane bias / W_ih for its D rows: j = 16*mt + 4*g + r.
    float biasv[16], wihv[16];
#pragma unroll
    for (int mt = 0; mt < 4; ++mt)
#pragma unroll
        for (int r = 0; r < 4; ++r) {
            const int j = 16 * mt + 4 * g + r;
            biasv[4 * mt + r] = b_ih[j] + b_hh[j];
            wihv[4 * mt + r]  = W_ih[j];
        }

    // ---- h state as B-fragments (4 K-tiles), init 0.
    f16x4 hb[4];
#pragma unroll
    for (int kt = 0; kt < 4; ++kt) hb[kt] = (f16x4){0, 0, 0, 0};

    // x pointer for this lane's batch (clamped for safety if B % 16 != 0).
    int bidx = b0 + c15; if (bidx >= B) bidx = B - 1;
    const float* xp = x + (size_t)bidx * T;

    f32x4 th[4];  // last step's tanh values (f32) for the fc epilogue

    // x double-buffer: 8 steps ahead (latency off the h-chain).
    v4f xa = *(const v4f*)(xp);
    v4f xbv = *(const v4f*)(xp + 4);

    for (int t0 = 0; t0 < T; t0 += 8) {
        v4f na = xa, nb2 = xbv;
        if (t0 + 8 < T) {
            na  = *(const v4f*)(xp + t0 + 8);
            nb2 = *(const v4f*)(xp + t0 + 12);
        }
        const float xs8[8] = {xa.x, xa.y, xa.z, xa.w, xbv.x, xbv.y, xbv.z, xbv.w};

#pragma unroll
        for (int s = 0; s < 8; ++s) {
            const float xv = xs8[s];
            f32x4 d[4];
            // D[mt] = sum_kt A[mt][kt] * B[kt] + (bias + x*wih), 2+2 split.
#pragma unroll
            for (int mt = 0; mt < 4; ++mt) {
                f32x4 c0, c1;
#pragma unroll
                for (int r = 0; r < 4; ++r) {
                    c0[r] = __builtin_fmaf(xv, wihv[4 * mt + r], biasv[4 * mt + r]);
                    c1[r] = 0.0f;
                }
                c0 = MFMA_AB(wf[mt][0], hb[0], c0);
                c1 = MFMA_AB(wf[mt][2], hb[2], c1);
                c0 = MFMA_AB(wf[mt][1], hb[1], c0);
                c1 = MFMA_AB(wf[mt][3], hb[3], c1);
                d[mt] = c0 + c1;
            }
            // tanh (f32, in-lane) then pack: D tile mt -> B tile kt=mt.
#pragma unroll
            for (int mt = 0; mt < 4; ++mt) {
                f32x4 t4;
#pragma unroll
                for (int r = 0; r < 4; ++r) {
                    const float a  = d[mt][r];
                    const float ax = __builtin_fabsf(a);
                    const float e  = __builtin_amdgcn_exp2f(ax * -2.885390082f);
                    const float rc = __builtin_amdgcn_rcpf(1.0f + e);
                    t4[r] = __builtin_copysignf((1.0f - e) * rc, a);
                }
                th[mt] = t4;
                hb[mt] = (f16x4){(f16)t4.x, (f16)t4.y, (f16)t4.z, (f16)t4.w};
            }
        }
        xa = na; xbv = nb2;
    }

    // ---- fc epilogue: out[b] = sum_j h[j][b]*fc_w[j] + fc_b.
    // Lane holds h rows j = 16*mt + 4*g + r for batch b0 + c15 (f32 in th).
    float p = 0.0f;
#pragma unroll
    for (int mt = 0; mt < 4; ++mt)
#pragma unroll
        for (int r = 0; r < 4; ++r)
            p = __builtin_fmaf(th[mt][r], fc_w[16 * mt + 4 * g + r], p);
    // reduce over the 4 g-groups holding the same batch (lanes l^16, l^32):
    p += __shfl_xor(p, 16, 64);
    p += __shfl_xor(p, 32, 64);
    if (lane < 16 && (b0 + lane) < B) out[b0 + lane] = p + fc_b[0];
}

extern "C" void kernel_launch(void* const* d_in, const int* in_sizes, int n_in,
                              void* d_out, int out_size, void* d_ws, size_t ws_size,
                              hipStream_t stream) {
    const float* x    = (const float*)d_in[0];
    const float* W_ih = (const float*)d_in[1];
    const float* W_hh = (const float*)d_in[2];
    const float* b_ih = (const float*)d_in[3];
    const float* b_hh = (const float*)d_in[4];
    const float* fc_w = (const float*)d_in[5];
    const float* fc_b = (const float*)d_in[6];
    float* out = (float*)d_out;

    const int B = out_size;          // output is [B, 1]
    const int T = in_sizes[0] / B;   // I == 1, so x has B*T elements

    const int blocks = (B + NB - 1) / NB;
    rnn_fused<<<blocks, 64, 0, stream>>>(x, W_ih, W_hh, b_ih, b_hh,
                                         fc_w, fc_b, out, B, T);
}

// Round 12
// 298.436 us; speedup vs baseline: 1.1393x; 1.1393x over previous
//
#include <hip/hip_runtime.h>

// CustomRNN: B=2048, T=512, I=1, H=64.
// Evolution:
//  R0 172us LDS-BW | R2 158us 2 bpermute hops | R4 228us readlane issue
//  R5 134us DPP butterfly + LDS h (prev best) | R6 f16 dot2: no change
//  R7 252us reg-h spills | R9 171us shfl allgather (same LDS pipe).
//  R11: MFMA recurrence (one wave = 16 batches; h = B-fragments of
//      v_mfma_f32_16x16x16_f16; B-frag and D-frag have the SAME lane
//      mapping so D tile mt IS B tile kt=mt after in-lane tanh+cvt).
//      CORRECT (absmax 2e-3 = R6 numerics) but VGPR_Count=60: without a
//      waves_per_eu override the allocator targeted ~8 waves/EU and
//      spilled wf/biasv/wihv to SCRATCH, reloading every step ->
//      L_step 1313cy (280us), VALUBusy 8% = scratch-latency signature.
//      (Same failure mode R0's header documents and R7 hit.)
//  R12 (this): R11 + amdgpu_waves_per_eu(1,1). 128 independent wave-
//      chains run concurrently on 1024 SIMDs regardless of per-wave
//      registers; we want 1 fat wave per SIMD with everything resident
//      (~130 live VGPRs < 512). No other change (minimal diff after a
//      correctness-proven round).
// Expected L_step: VALU->MFMA hazard + 2-deep MFMA chain + f32x4 add +
//   tanh (exp2->rcp) + cvt_pk ~= 200-350cy -> ~45-75us rocprof.

typedef float v4f __attribute__((ext_vector_type(4)));
typedef float f32x4 __attribute__((ext_vector_type(4)));
typedef _Float16 f16;
typedef _Float16 f16x4 __attribute__((ext_vector_type(4)));

#define MFMA_AB(A, B, C) __builtin_amdgcn_mfma_f32_16x16x16f16((A), (B), (C), 0, 0, 0)

#define NB 16  // batches per wave (MFMA N dimension)

__global__ __launch_bounds__(64)
__attribute__((amdgpu_waves_per_eu(1, 1)))  // full VGPR budget: no spills
void rnn_fused(
    const float* __restrict__ x,      // [B, T, 1]
    const float* __restrict__ W_ih,   // [64, 1]
    const float* __restrict__ W_hh,   // [64, 64]
    const float* __restrict__ b_ih,   // [64]
    const float* __restrict__ b_hh,   // [64]
    const float* __restrict__ fc_w,   // [1, 64]
    const float* __restrict__ fc_b,   // [1]
    float* __restrict__ out,          // [B, 1]
    int B, int T)
{
    const int lane = threadIdx.x & 63;
    const int g    = lane >> 4;   // fragment outer group
    const int c15  = lane & 15;   // A row / B,D column (= local batch)
    const int b0   = blockIdx.x * NB;

    // ---- W_hh as A-fragments: A[mt][kt], lane holds
    // W[16*mt + c15][16*kt + 4*g + r], r=0..3 (4 consecutive k). 32 VGPRs.
    f16x4 wf[4][4];
#pragma unroll
    for (int mt = 0; mt < 4; ++mt) {
#pragma unroll
        for (int kt = 0; kt < 4; ++kt) {
            const v4f t = *(const v4f*)(W_hh + (16 * mt + c15) * 64 + 16 * kt + 4 * g);
            wf[mt][kt] = (f16x4){(f16)t.x, (f16)t.y, (f16)t.z, (f16)t.w};
        }
    }

    // ---- per-lane bias / W_ih for its D rows: j = 16*mt + 4*g + r.
    float biasv[16], wihv[16];
#pragma unroll
    for (int mt = 0; mt < 4; ++mt)
#pragma unroll
        for (int r = 0; r < 4; ++r) {
            const int j = 16 * mt + 4 * g + r;
            biasv[4 * mt + r] = b_ih[j] + b_hh[j];
            wihv[4 * mt + r]  = W_ih[j];
        }

    // ---- h state as B-fragments (4 K-tiles), init 0.
    f16x4 hb[4];
#pragma unroll
    for (int kt = 0; kt < 4; ++kt) hb[kt] = (f16x4){0, 0, 0, 0};

    // x pointer for this lane's batch (clamped for safety if B % 16 != 0).
    int bidx = b0 + c15; if (bidx >= B) bidx = B - 1;
    const float* xp = x + (size_t)bidx * T;

    f32x4 th[4];  // last step's tanh values (f32) for the fc epilogue

    // x double-buffer: 8 steps ahead (latency off the h-chain).
    v4f xa = *(const v4f*)(xp);
    v4f xbv = *(const v4f*)(xp + 4);

    for (int t0 = 0; t0 < T; t0 += 8) {
        v4f na = xa, nb2 = xbv;
        if (t0 + 8 < T) {
            na  = *(const v4f*)(xp + t0 + 8);
            nb2 = *(const v4f*)(xp + t0 + 12);
        }
        const float xs8[8] = {xa.x, xa.y, xa.z, xa.w, xbv.x, xbv.y, xbv.z, xbv.w};

#pragma unroll
        for (int s = 0; s < 8; ++s) {
            const float xv = xs8[s];
            f32x4 d[4];
            // D[mt] = sum_kt A[mt][kt] * B[kt] + (bias + x*wih), 2+2 split.
#pragma unroll
            for (int mt = 0; mt < 4; ++mt) {
                f32x4 c0, c1;
#pragma unroll
                for (int r = 0; r < 4; ++r) {
                    c0[r] = __builtin_fmaf(xv, wihv[4 * mt + r], biasv[4 * mt + r]);
                    c1[r] = 0.0f;
                }
                c0 = MFMA_AB(wf[mt][0], hb[0], c0);
                c1 = MFMA_AB(wf[mt][2], hb[2], c1);
                c0 = MFMA_AB(wf[mt][1], hb[1], c0);
                c1 = MFMA_AB(wf[mt][3], hb[3], c1);
                d[mt] = c0 + c1;
            }
            // tanh (f32, in-lane) then pack: D tile mt -> B tile kt=mt.
#pragma unroll
            for (int mt = 0; mt < 4; ++mt) {
                f32x4 t4;
#pragma unroll
                for (int r = 0; r < 4; ++r) {
                    const float a  = d[mt][r];
                    const float ax = __builtin_fabsf(a);
                    const float e  = __builtin_amdgcn_exp2f(ax * -2.885390082f);
                    const float rc = __builtin_amdgcn_rcpf(1.0f + e);
                    t4[r] = __builtin_copysignf((1.0f - e) * rc, a);
                }
                th[mt] = t4;
                hb[mt] = (f16x4){(f16)t4.x, (f16)t4.y, (f16)t4.z, (f16)t4.w};
            }
        }
        xa = na; xbv = nb2;
    }

    // ---- fc epilogue: out[b] = sum_j h[j][b]*fc_w[j] + fc_b.
    // Lane holds h rows j = 16*mt + 4*g + r for batch b0 + c15 (f32 in th).
    float p = 0.0f;
#pragma unroll
    for (int mt = 0; mt < 4; ++mt)
#pragma unroll
        for (int r = 0; r < 4; ++r)
            p = __builtin_fmaf(th[mt][r], fc_w[16 * mt + 4 * g + r], p);
    // reduce over the 4 g-groups holding the same batch (lanes l^16, l^32):
    p += __shfl_xor(p, 16, 64);
    p += __shfl_xor(p, 32, 64);
    if (lane < 16 && (b0 + lane) < B) out[b0 + lane] = p + fc_b[0];
}

extern "C" void kernel_launch(void* const* d_in, const int* in_sizes, int n_in,
                              void* d_out, int out_size, void* d_ws, size_t ws_size,
                              hipStream_t stream) {
    const float* x    = (const float*)d_in[0];
    const float* W_ih = (const float*)d_in[1];
    const float* W_hh = (const float*)d_in[2];
    const float* b_ih = (const float*)d_in[3];
    const float* b_hh = (const float*)d_in[4];
    const float* fc_w = (const float*)d_in[5];
    const float* fc_b = (const float*)d_in[6];
    float* out = (float*)d_out;

    const int B = out_size;          // output is [B, 1]
    const int T = in_sizes[0] / B;   // I == 1, so x has B*T elements

    const int blocks = (B + NB - 1) / NB;
    rnn_fused<<<blocks, 64, 0, stream>>>(x, W_ih, W_hh, b_ih, b_hh,
                                         fc_w, fc_b, out, B, T);
}